// Round 4
// baseline (257.446 us; speedup 1.0000x reference)
//
#include <hip/hip_runtime.h>
#include <math.h>

#define NV 32000
#define NE 1024
#define NH 1024
#define NS 1024
#define NB 64

typedef __attribute__((ext_vector_type(4))) float f32x4;
typedef __attribute__((ext_vector_type(8))) short bf16x8;

// d_out layout (floats): output(B,V) | context(B,H) | hidden(1,B,H) | attn(B,1,S)
#define OUT_CTX   (NB*NV)
#define OUT_HID   (NB*NV + NB*NH)
#define OUT_ATTN  (NB*NV + 2*NB*NH)

// workspace layout (float offsets)
#define WS_XA   0                          // ushort[64][2048] x0 bf16
#define WS_HA   (WS_XA + 65536)            // ushort[64][1024] h_prev bf16
#define WS_PG   (WS_HA + 32768)            // f32 [6][3072][64] GRU partials
#define WS_E    (WS_PG + 6*3072*64)        // f32 [64][1024] raw energies
#define WS_PCTX (WS_E + NB*NS)             // f32 [64][64][1024] attn ctx partials (b, g, h)
#define WS_ML   (WS_PCTX + 64*64*1024)     // f32 [64][64][2]  (m, l) per (b, g)
#define WS_LA   (WS_ML + 8192)             // ushort[64][2048] concat(h,ctx) bf16
#define WS_P    (WS_LA + 65536)            // f32 [4][64][32000] logits partials

__device__ inline unsigned short f2bf(float f) {
    unsigned u = __builtin_bit_cast(unsigned, f);
    u += 0x7fffu + ((u >> 16) & 1u);   // RNE
    return (unsigned short)(u >> 16);
}

__device__ inline bf16x8 cvt8(float4 a, float4 b) {
    bf16x8 r;
    r[0] = (short)f2bf(a.x); r[1] = (short)f2bf(a.y);
    r[2] = (short)f2bf(a.z); r[3] = (short)f2bf(a.w);
    r[4] = (short)f2bf(b.x); r[5] = (short)f2bf(b.y);
    r[6] = (short)f2bf(b.z); r[7] = (short)f2bf(b.w);
    return r;
}

__device__ inline void store_bf4(unsigned short* p, float4 v) {
    ushort4 u = make_ushort4(f2bf(v.x), f2bf(v.y), f2bf(v.z), f2bf(v.w));
    *(ushort4*)p = u;
}

// ---------------- prep: x0 = concat(emb, lctx) -> bf16; h_prev -> bf16 ----------------
__global__ void k_prep(const int* __restrict__ wi, const float* __restrict__ lctx,
                       const float* __restrict__ lhid, const float* __restrict__ emb,
                       float* __restrict__ ws) {
    int b = blockIdx.x, t = threadIdx.x;           // 64 x 256
    unsigned short* XA = (unsigned short*)(ws + WS_XA);
    unsigned short* HA = (unsigned short*)(ws + WS_HA);
    long row = wi[b];
    float4 e4 = ((const float4*)(emb + row*NE))[t];
    float4 c4 = ((const float4*)(lctx + (long)b*NH))[t];
    float4 h4 = ((const float4*)(lhid + (long)b*NH))[t];
    store_bf4(XA + (long)b*2048 + t*4,        e4);
    store_bf4(XA + (long)b*2048 + 1024 + t*4, c4);
    store_bf4(HA + (long)b*1024 + t*4,        h4);
}

// ---------------- GRU GEMM via MFMA: partials [6][3072][64] ----------------
__global__ void __launch_bounds__(256) k_gru_mfma(const float* __restrict__ w_ih,
                                                  const float* __restrict__ w_hh,
                                                  float* __restrict__ ws) {
    int wave = blockIdx.x*4 + (threadIdx.x >> 6);   // 1152 waves
    int lane = threadIdx.x & 63;
    int c = wave % 6, ntile = wave / 6;
    int n0 = ntile * 16;
    int col = lane & 15, kg = lane >> 4;
    const unsigned short* XA = (const unsigned short*)(ws + WS_XA);
    const unsigned short* HA = (const unsigned short*)(ws + WS_HA);
    const float* Wp; const unsigned short* Ap; int ld, kbase;
    if (c < 4) { Wp = w_ih; Ap = XA; ld = 2048; kbase = c*512; }
    else       { Wp = w_hh; Ap = HA; ld = 1024; kbase = (c-4)*512; }
    const float* wrow = Wp + (long)(n0 + col)*ld + kbase + kg*8;
    f32x4 acc[4];
    #pragma unroll
    for (int m = 0; m < 4; m++) acc[m] = (f32x4){0.f,0.f,0.f,0.f};
    #pragma unroll 4
    for (int k0 = 0; k0 < 512; k0 += 32) {
        float4 wa = *(const float4*)(wrow + k0);
        float4 wb = *(const float4*)(wrow + k0 + 4);
        bf16x8 bf = cvt8(wa, wb);
        #pragma unroll
        for (int m = 0; m < 4; m++) {
            bf16x8 af = *(const bf16x8*)(Ap + (long)(m*16 + col)*ld + kbase + k0 + kg*8);
            acc[m] = __builtin_amdgcn_mfma_f32_16x16x32_bf16(af, bf, acc[m], 0, 0, 0);
        }
    }
    float* pg = ws + WS_PG + ((long)c*3072 + n0 + col)*64;
    #pragma unroll
    for (int m = 0; m < 4; m++)
        #pragma unroll
        for (int j = 0; j < 4; j++)
            pg[m*16 + kg*4 + j] = acc[m][j];
}

// ---------------- GRU gates ----------------
__global__ void k_gates(const float* __restrict__ wsc, const float* __restrict__ b_ih,
                        const float* __restrict__ b_hh, const float* __restrict__ lhid,
                        float* __restrict__ out, float* __restrict__ ws) {
    int g = blockIdx.x*256 + threadIdx.x;  // 65536 threads
    int b = g & 63, i = g >> 6;
    float gir=0.f, giz=0.f, gin=0.f, ghr=0.f, ghz=0.f, ghn=0.f;
    #pragma unroll
    for (int c = 0; c < 4; c++) {
        long base = WS_PG + (long)c*3072*64;
        gir += wsc[base + ((long)(0*NH + i))*64 + b];
        giz += wsc[base + ((long)(1*NH + i))*64 + b];
        gin += wsc[base + ((long)(2*NH + i))*64 + b];
    }
    #pragma unroll
    for (int c = 4; c < 6; c++) {
        long base = WS_PG + (long)c*3072*64;
        ghr += wsc[base + ((long)(0*NH + i))*64 + b];
        ghz += wsc[base + ((long)(1*NH + i))*64 + b];
        ghn += wsc[base + ((long)(2*NH + i))*64 + b];
    }
    gir += b_ih[i];        ghr += b_hh[i];
    giz += b_ih[NH + i];   ghz += b_hh[NH + i];
    gin += b_ih[2*NH + i]; ghn += b_hh[2*NH + i];
    float r = 1.f / (1.f + expf(-(gir + ghr)));
    float z = 1.f / (1.f + expf(-(giz + ghz)));
    float n = tanhf(gin + r*ghn);
    float hp = lhid[(long)b*NH + i];
    float h = (1.f - z)*n + z*hp;
    out[OUT_HID + (long)b*NH + i] = h;
    ((unsigned short*)(ws + WS_LA))[(long)b*2048 + i] = f2bf(h);
}

// ---------------- fused attention: single encoder pass, online softmax ----------------
// wave handles (b, g): s in [g*16, g*16+16); lane covers h = it*256+lane*4
// register double-buffer: next s's 4 float4 loads issued before current softmax chain
__global__ void __launch_bounds__(256) k_attn(const float* __restrict__ enc,
                                              const float* __restrict__ out,
                                              float* __restrict__ ws) {
    int widx = threadIdx.x >> 6, lane = threadIdx.x & 63;
    int b = blockIdx.x >> 4;                 // 1024 blocks
    int g = (blockIdx.x & 15)*4 + widx;      // 0..63
    const float4* hr = (const float4*)(out + OUT_HID + (long)b*NH);
    float4 h0 = hr[lane], h1 = hr[64+lane], h2 = hr[128+lane], h3 = hr[192+lane];
    float m = -1e30f, l = 0.f;
    float4 c0 = make_float4(0,0,0,0), c1 = c0, c2 = c0, c3 = c0;
    const float4* vp = (const float4*)(enc + ((long)(g*16)*NB + b)*NH);
    const long sstr = (long)NB*NH/4;         // float4 stride between s
    float4 a0 = vp[lane], a1 = vp[64+lane], a2 = vp[128+lane], a3 = vp[192+lane];
    #pragma unroll
    for (int si = 0; si < 16; si++) {
        float4 n0 = a0, n1 = a1, n2 = a2, n3 = a3;
        if (si < 15) {
            const float4* np = vp + (long)(si+1)*sstr;
            n0 = np[lane]; n1 = np[64+lane]; n2 = np[128+lane]; n3 = np[192+lane];
        }
        float d = a0.x*h0.x + a0.y*h0.y + a0.z*h0.z + a0.w*h0.w
                + a1.x*h1.x + a1.y*h1.y + a1.z*h1.z + a1.w*h1.w
                + a2.x*h2.x + a2.y*h2.y + a2.z*h2.z + a2.w*h2.w
                + a3.x*h3.x + a3.y*h3.y + a3.z*h3.z + a3.w*h3.w;
        #pragma unroll
        for (int o = 32; o > 0; o >>= 1) d += __shfl_xor(d, o);
        if (lane == 0) ws[WS_E + (long)b*NS + g*16 + si] = d;
        float mnew = fmaxf(m, d);
        float coef = expf(m - mnew);
        float p = expf(d - mnew);
        l = l*coef + p;
        c0.x = c0.x*coef + p*a0.x; c0.y = c0.y*coef + p*a0.y;
        c0.z = c0.z*coef + p*a0.z; c0.w = c0.w*coef + p*a0.w;
        c1.x = c1.x*coef + p*a1.x; c1.y = c1.y*coef + p*a1.y;
        c1.z = c1.z*coef + p*a1.z; c1.w = c1.w*coef + p*a1.w;
        c2.x = c2.x*coef + p*a2.x; c2.y = c2.y*coef + p*a2.y;
        c2.z = c2.z*coef + p*a2.z; c2.w = c2.w*coef + p*a2.w;
        c3.x = c3.x*coef + p*a3.x; c3.y = c3.y*coef + p*a3.y;
        c3.z = c3.z*coef + p*a3.z; c3.w = c3.w*coef + p*a3.w;
        m = mnew;
        a0 = n0; a1 = n1; a2 = n2; a3 = n3;
    }
    float* pc = ws + WS_PCTX + ((long)b*64 + g)*1024;
    *(float4*)(pc + 0*256 + lane*4) = c0;
    *(float4*)(pc + 1*256 + lane*4) = c1;
    *(float4*)(pc + 2*256 + lane*4) = c2;
    *(float4*)(pc + 3*256 + lane*4) = c3;
    if (lane == 0) {
        ws[WS_ML + ((long)b*64 + g)*2]     = m;
        ws[WS_ML + ((long)b*64 + g)*2 + 1] = l;
    }
}

// ---------------- attn reduce: combine partials; emit ctx, attn weights, bf16 LA ----------------
__global__ void k_attn_reduce(const float* __restrict__ wsc, float* __restrict__ out,
                              float* __restrict__ ws) {
    int b = blockIdx.x, t = threadIdx.x;     // 64 x 256
    __shared__ float sm[64], sl[64], sc[64];
    __shared__ float sM, sinvL;
    if (t < 64) {
        sm[t] = wsc[WS_ML + ((long)b*64 + t)*2];
        sl[t] = wsc[WS_ML + ((long)b*64 + t)*2 + 1];
    }
    __syncthreads();
    if (t == 0) {
        float M = -1e30f;
        for (int g = 0; g < 64; g++) M = fmaxf(M, sm[g]);
        float L = 0.f;
        for (int g = 0; g < 64; g++) L += sl[g]*expf(sm[g] - M);
        sM = M; sinvL = 1.f/L;
    }
    __syncthreads();
    float M = sM, invL = sinvL;
    if (t < 64) sc[t] = expf(sm[t] - M);
    __syncthreads();
    float4 acc = make_float4(0.f,0.f,0.f,0.f);
    for (int g = 0; g < 64; g++) {
        float c = sc[g];
        float4 p = *(const float4*)(wsc + WS_PCTX + ((long)b*64 + g)*1024 + t*4);
        acc.x += c*p.x; acc.y += c*p.y; acc.z += c*p.z; acc.w += c*p.w;
    }
    acc.x *= invL; acc.y *= invL; acc.z *= invL; acc.w *= invL;
    *(float4*)(out + OUT_CTX + (long)b*NH + t*4) = acc;
    store_bf4((unsigned short*)(ws + WS_LA) + (long)b*2048 + 1024 + t*4, acc);
    float4 e4 = *(const float4*)(wsc + WS_E + (long)b*NS + t*4);
    *(float4*)(out + OUT_ATTN + (long)b*NS + t*4) =
        make_float4(expf(e4.x-M)*invL, expf(e4.y-M)*invL,
                    expf(e4.z-M)*invL, expf(e4.w-M)*invL);
}

// ---------------- logits via MFMA, split-K x4: partials [4][64][32000] ----------------
__global__ void __launch_bounds__(256) k_logits_mfma(const float* __restrict__ oW,
                                                     const float* __restrict__ wsc,
                                                     float* __restrict__ ws) {
    int wave = blockIdx.x*4 + (threadIdx.x >> 6);   // 8000 waves
    int lane = threadIdx.x & 63;
    int q = wave & 3, vt = wave >> 2;
    int v0 = vt * 16, kbase = q * 512;
    int col = lane & 15, kg = lane >> 4;
    const unsigned short* LA = (const unsigned short*)(wsc + WS_LA);
    const float* wrow = oW + (long)(v0 + col)*2048 + kbase + kg*8;
    f32x4 acc[4];
    #pragma unroll
    for (int m = 0; m < 4; m++) acc[m] = (f32x4){0.f,0.f,0.f,0.f};
    #pragma unroll 4
    for (int k0 = 0; k0 < 512; k0 += 32) {
        float4 wa = *(const float4*)(wrow + k0);
        float4 wb = *(const float4*)(wrow + k0 + 4);
        bf16x8 bf = cvt8(wa, wb);
        #pragma unroll
        for (int m = 0; m < 4; m++) {
            bf16x8 af = *(const bf16x8*)(LA + (long)(m*16 + col)*2048 + kbase + k0 + kg*8);
            acc[m] = __builtin_amdgcn_mfma_f32_16x16x32_bf16(af, bf, acc[m], 0, 0, 0);
        }
    }
    float* P = ws + WS_P + (long)q*(64L*32000);
    #pragma unroll
    for (int m = 0; m < 4; m++)
        #pragma unroll
        for (int j = 0; j < 4; j++)
            P[(long)(m*16 + kg*4 + j)*NV + v0 + col] = acc[m][j];
}

// ---------------- fused: sum partials + bias, then log_softmax ----------------
__global__ void k_logsoftmax(const float* __restrict__ wsc, const float* __restrict__ ob,
                             float* __restrict__ out) {
    int b = blockIdx.x, t = threadIdx.x;  // 64 x 256
    const float* P0 = wsc + WS_P + (long)b*NV;
    const float* P1 = wsc + WS_P + 1L*64*32000 + (long)b*NV;
    const float* P2 = wsc + WS_P + 2L*64*32000 + (long)b*NV;
    const float* P3 = wsc + WS_P + 3L*64*32000 + (long)b*NV;
    float* row = out + (long)b*NV;
    __shared__ float red[256];
    float m = -1e30f;
    for (int i = t*4; i < NV; i += 1024) {
        float4 a = *(const float4*)(P0 + i);
        float4 c = *(const float4*)(P1 + i);
        float4 d = *(const float4*)(P2 + i);
        float4 e = *(const float4*)(P3 + i);
        float4 bb = *(const float4*)(ob + i);
        float4 v = make_float4(a.x+c.x+d.x+e.x+bb.x, a.y+c.y+d.y+e.y+bb.y,
                               a.z+c.z+d.z+e.z+bb.z, a.w+c.w+d.w+e.w+bb.w);
        *(float4*)(row + i) = v;
        m = fmaxf(m, fmaxf(fmaxf(v.x, v.y), fmaxf(v.z, v.w)));
    }
    red[t] = m; __syncthreads();
    for (int o = 128; o > 0; o >>= 1) { if (t < o) red[t] = fmaxf(red[t], red[t+o]); __syncthreads(); }
    float M = red[0]; __syncthreads();
    float ss = 0.f;
    for (int i = t*4; i < NV; i += 1024) {
        float4 v = *(const float4*)(row + i);
        ss += expf(v.x-M) + expf(v.y-M) + expf(v.z-M) + expf(v.w-M);
    }
    red[t] = ss; __syncthreads();
    for (int o = 128; o > 0; o >>= 1) { if (t < o) red[t] += red[t+o]; __syncthreads(); }
    float lse = M + logf(red[0]);
    for (int i = t*4; i < NV; i += 1024) {
        float4 v = *(const float4*)(row + i);
        *(float4*)(row + i) = make_float4(v.x-lse, v.y-lse, v.z-lse, v.w-lse);
    }
}

extern "C" void kernel_launch(void* const* d_in, const int* in_sizes, int n_in,
                              void* d_out, int out_size, void* d_ws, size_t ws_size,
                              hipStream_t stream) {
    const int*   wi   = (const int*)d_in[0];
    const float* lctx = (const float*)d_in[1];
    const float* lhid = (const float*)d_in[2];
    const float* enc  = (const float*)d_in[3];
    const float* emb  = (const float*)d_in[4];
    const float* w_ih = (const float*)d_in[5];
    const float* w_hh = (const float*)d_in[6];
    const float* b_ih = (const float*)d_in[7];
    const float* b_hh = (const float*)d_in[8];
    const float* oW   = (const float*)d_in[9];
    const float* ob   = (const float*)d_in[10];
    float* out = (float*)d_out;
    float* ws  = (float*)d_ws;

    hipLaunchKernelGGL(k_prep,        dim3(64),   dim3(256), 0, stream, wi, lctx, lhid, emb, ws);
    hipLaunchKernelGGL(k_gru_mfma,    dim3(288),  dim3(256), 0, stream, w_ih, w_hh, ws);
    hipLaunchKernelGGL(k_gates,       dim3(256),  dim3(256), 0, stream, ws, b_ih, b_hh, lhid, out, ws);
    hipLaunchKernelGGL(k_attn,        dim3(1024), dim3(256), 0, stream, enc, out, ws);
    hipLaunchKernelGGL(k_attn_reduce, dim3(64),   dim3(256), 0, stream, ws, out, ws);
    hipLaunchKernelGGL(k_logits_mfma, dim3(2000), dim3(256), 0, stream, oW, ws, ws);
    hipLaunchKernelGGL(k_logsoftmax,  dim3(64),   dim3(256), 0, stream, ws, ob, out);
}

// Round 5
// 236.290 us; speedup vs baseline: 1.0895x; 1.0895x over previous
//
#include <hip/hip_runtime.h>
#include <math.h>

#define NV 32000
#define NE 1024
#define NH 1024
#define NS 1024
#define NB 64

typedef __attribute__((ext_vector_type(4))) float f32x4;
typedef __attribute__((ext_vector_type(8))) short bf16x8;

// d_out layout (floats): output(B,V) | context(B,H) | hidden(1,B,H) | attn(B,1,S)
#define OUT_CTX   (NB*NV)
#define OUT_HID   (NB*NV + NB*NH)
#define OUT_ATTN  (NB*NV + 2*NB*NH)

// workspace layout (float offsets)
#define WS_XA   0                          // ushort[64][2048] x0 bf16
#define WS_HA   (WS_XA + 65536)            // ushort[64][1024] h_prev bf16
#define WS_PG   (WS_HA + 32768)            // f32 [12][3072][64] GRU partials
#define WS_E    (WS_PG + 12*3072*64)       // f32 [64][1024] raw energies
#define WS_PCTX (WS_E + NB*NS)             // f32 [64][64][1024] attn ctx partials (b, g, h)
#define WS_ML   (WS_PCTX + 64*64*1024)     // f32 [64][64][2]  (m, l) per (b, g)
#define WS_LA   (WS_ML + 8192)             // ushort[64][2048] concat(h,ctx) bf16
#define WS_P    (WS_LA + 65536)            // f32 [2][2000][1024] logits partials, tile-blocked

__device__ inline unsigned short f2bf(float f) {
    unsigned u = __builtin_bit_cast(unsigned, f);
    u += 0x7fffu + ((u >> 16) & 1u);   // RNE
    return (unsigned short)(u >> 16);
}

__device__ inline bf16x8 cvt8(float4 a, float4 b) {
    bf16x8 r;
    r[0] = (short)f2bf(a.x); r[1] = (short)f2bf(a.y);
    r[2] = (short)f2bf(a.z); r[3] = (short)f2bf(a.w);
    r[4] = (short)f2bf(b.x); r[5] = (short)f2bf(b.y);
    r[6] = (short)f2bf(b.z); r[7] = (short)f2bf(b.w);
    return r;
}

__device__ inline void store_bf4(unsigned short* p, float4 v) {
    ushort4 u = make_ushort4(f2bf(v.x), f2bf(v.y), f2bf(v.z), f2bf(v.w));
    *(ushort4*)p = u;
}

// ---------------- prep: x0 = concat(emb, lctx) -> bf16; h_prev -> bf16 ----------------
__global__ void k_prep(const int* __restrict__ wi, const float* __restrict__ lctx,
                       const float* __restrict__ lhid, const float* __restrict__ emb,
                       float* __restrict__ ws) {
    int b = blockIdx.x, t = threadIdx.x;           // 64 x 256
    unsigned short* XA = (unsigned short*)(ws + WS_XA);
    unsigned short* HA = (unsigned short*)(ws + WS_HA);
    long row = wi[b];
    float4 e4 = ((const float4*)(emb + row*NE))[t];
    float4 c4 = ((const float4*)(lctx + (long)b*NH))[t];
    float4 h4 = ((const float4*)(lhid + (long)b*NH))[t];
    store_bf4(XA + (long)b*2048 + t*4,        e4);
    store_bf4(XA + (long)b*2048 + 1024 + t*4, c4);
    store_bf4(HA + (long)b*1024 + t*4,        h4);
}

// ---------------- GRU GEMM via MFMA: partials [12][3072][64], K-chunks of 256 ----------------
__global__ void __launch_bounds__(256) k_gru_mfma(const float* __restrict__ w_ih,
                                                  const float* __restrict__ w_hh,
                                                  float* __restrict__ ws) {
    int wave = blockIdx.x*4 + (threadIdx.x >> 6);   // 2304 waves (576 blocks)
    int lane = threadIdx.x & 63;
    int c = wave % 12, ntile = wave / 12;           // 192 n-tiles
    int n0 = ntile * 16;
    int col = lane & 15, kg = lane >> 4;
    const unsigned short* XA = (const unsigned short*)(ws + WS_XA);
    const unsigned short* HA = (const unsigned short*)(ws + WS_HA);
    const float* Wp; const unsigned short* Ap; int ld, kbase;
    if (c < 8) { Wp = w_ih; Ap = XA; ld = 2048; kbase = c*256; }
    else       { Wp = w_hh; Ap = HA; ld = 1024; kbase = (c-8)*256; }
    const float* wrow = Wp + (long)(n0 + col)*ld + kbase + kg*8;
    f32x4 acc[4];
    #pragma unroll
    for (int m = 0; m < 4; m++) acc[m] = (f32x4){0.f,0.f,0.f,0.f};
    #pragma unroll 4
    for (int k0 = 0; k0 < 256; k0 += 32) {
        float4 wa = *(const float4*)(wrow + k0);
        float4 wb = *(const float4*)(wrow + k0 + 4);
        bf16x8 bf = cvt8(wa, wb);
        #pragma unroll
        for (int m = 0; m < 4; m++) {
            bf16x8 af = *(const bf16x8*)(Ap + (long)(m*16 + col)*ld + kbase + k0 + kg*8);
            acc[m] = __builtin_amdgcn_mfma_f32_16x16x32_bf16(af, bf, acc[m], 0, 0, 0);
        }
    }
    float* pg = ws + WS_PG + ((long)c*3072 + n0 + col)*64;
    #pragma unroll
    for (int m = 0; m < 4; m++)
        #pragma unroll
        for (int j = 0; j < 4; j++)
            pg[m*16 + kg*4 + j] = acc[m][j];
}

// ---------------- GRU gates ----------------
__global__ void k_gates(const float* __restrict__ wsc, const float* __restrict__ b_ih,
                        const float* __restrict__ b_hh, const float* __restrict__ lhid,
                        float* __restrict__ out, float* __restrict__ ws) {
    int g = blockIdx.x*256 + threadIdx.x;  // 65536 threads
    int b = g & 63, i = g >> 6;
    float gir=0.f, giz=0.f, gin=0.f, ghr=0.f, ghz=0.f, ghn=0.f;
    #pragma unroll
    for (int c = 0; c < 8; c++) {
        long base = WS_PG + (long)c*3072*64;
        gir += wsc[base + ((long)(0*NH + i))*64 + b];
        giz += wsc[base + ((long)(1*NH + i))*64 + b];
        gin += wsc[base + ((long)(2*NH + i))*64 + b];
    }
    #pragma unroll
    for (int c = 8; c < 12; c++) {
        long base = WS_PG + (long)c*3072*64;
        ghr += wsc[base + ((long)(0*NH + i))*64 + b];
        ghz += wsc[base + ((long)(1*NH + i))*64 + b];
        ghn += wsc[base + ((long)(2*NH + i))*64 + b];
    }
    gir += b_ih[i];        ghr += b_hh[i];
    giz += b_ih[NH + i];   ghz += b_hh[NH + i];
    gin += b_ih[2*NH + i]; ghn += b_hh[2*NH + i];
    float r = 1.f / (1.f + expf(-(gir + ghr)));
    float z = 1.f / (1.f + expf(-(giz + ghz)));
    float n = tanhf(gin + r*ghn);
    float hp = lhid[(long)b*NH + i];
    float h = (1.f - z)*n + z*hp;
    out[OUT_HID + (long)b*NH + i] = h;
    ((unsigned short*)(ws + WS_LA))[(long)b*2048 + i] = f2bf(h);
}

// ---------------- fused attention: single encoder pass, online softmax ----------------
__global__ void __launch_bounds__(256) k_attn(const float* __restrict__ enc,
                                              const float* __restrict__ out,
                                              float* __restrict__ ws) {
    int widx = threadIdx.x >> 6, lane = threadIdx.x & 63;
    int b = blockIdx.x >> 4;                 // 1024 blocks
    int g = (blockIdx.x & 15)*4 + widx;      // 0..63
    const float4* hr = (const float4*)(out + OUT_HID + (long)b*NH);
    float4 h0 = hr[lane], h1 = hr[64+lane], h2 = hr[128+lane], h3 = hr[192+lane];
    float m = -1e30f, l = 0.f;
    float4 c0 = make_float4(0,0,0,0), c1 = c0, c2 = c0, c3 = c0;
    const float4* vp = (const float4*)(enc + ((long)(g*16)*NB + b)*NH);
    const long sstr = (long)NB*NH/4;         // float4 stride between s
    float4 a0 = vp[lane], a1 = vp[64+lane], a2 = vp[128+lane], a3 = vp[192+lane];
    #pragma unroll
    for (int si = 0; si < 16; si++) {
        float4 n0 = a0, n1 = a1, n2 = a2, n3 = a3;
        if (si < 15) {
            const float4* np = vp + (long)(si+1)*sstr;
            n0 = np[lane]; n1 = np[64+lane]; n2 = np[128+lane]; n3 = np[192+lane];
        }
        float d = a0.x*h0.x + a0.y*h0.y + a0.z*h0.z + a0.w*h0.w
                + a1.x*h1.x + a1.y*h1.y + a1.z*h1.z + a1.w*h1.w
                + a2.x*h2.x + a2.y*h2.y + a2.z*h2.z + a2.w*h2.w
                + a3.x*h3.x + a3.y*h3.y + a3.z*h3.z + a3.w*h3.w;
        #pragma unroll
        for (int o = 32; o > 0; o >>= 1) d += __shfl_xor(d, o);
        if (lane == 0) ws[WS_E + (long)b*NS + g*16 + si] = d;
        float mnew = fmaxf(m, d);
        float coef = expf(m - mnew);
        float p = expf(d - mnew);
        l = l*coef + p;
        c0.x = c0.x*coef + p*a0.x; c0.y = c0.y*coef + p*a0.y;
        c0.z = c0.z*coef + p*a0.z; c0.w = c0.w*coef + p*a0.w;
        c1.x = c1.x*coef + p*a1.x; c1.y = c1.y*coef + p*a1.y;
        c1.z = c1.z*coef + p*a1.z; c1.w = c1.w*coef + p*a1.w;
        c2.x = c2.x*coef + p*a2.x; c2.y = c2.y*coef + p*a2.y;
        c2.z = c2.z*coef + p*a2.z; c2.w = c2.w*coef + p*a2.w;
        c3.x = c3.x*coef + p*a3.x; c3.y = c3.y*coef + p*a3.y;
        c3.z = c3.z*coef + p*a3.z; c3.w = c3.w*coef + p*a3.w;
        m = mnew;
        a0 = n0; a1 = n1; a2 = n2; a3 = n3;
    }
    float* pc = ws + WS_PCTX + ((long)b*64 + g)*1024;
    *(float4*)(pc + 0*256 + lane*4) = c0;
    *(float4*)(pc + 1*256 + lane*4) = c1;
    *(float4*)(pc + 2*256 + lane*4) = c2;
    *(float4*)(pc + 3*256 + lane*4) = c3;
    if (lane == 0) {
        ws[WS_ML + ((long)b*64 + g)*2]     = m;
        ws[WS_ML + ((long)b*64 + g)*2 + 1] = l;
    }
}

// ---------------- attn reduce (wide): 256 blocks = (b, quarter) ----------------
__global__ void k_attn_reduce(const float* __restrict__ wsc, float* __restrict__ out,
                              float* __restrict__ ws) {
    int b = blockIdx.x >> 2, q = blockIdx.x & 3;   // 256 blocks x 256 threads
    int t = threadIdx.x;
    __shared__ float sm[64], sl[64], sc[64];
    __shared__ float sM, sinvL;
    if (t < 64) {
        sm[t] = wsc[WS_ML + ((long)b*64 + t)*2];
        sl[t] = wsc[WS_ML + ((long)b*64 + t)*2 + 1];
    }
    __syncthreads();
    if (t == 0) {
        float M = -1e30f;
        for (int g = 0; g < 64; g++) M = fmaxf(M, sm[g]);
        float L = 0.f;
        for (int g = 0; g < 64; g++) L += sl[g]*expf(sm[g] - M);
        sM = M; sinvL = 1.f/L;
    }
    __syncthreads();
    float M = sM, invL = sinvL;
    if (t < 64) sc[t] = expf(sm[t] - M);
    __syncthreads();
    int h = q*256 + t;
    float acc = 0.f;
    #pragma unroll 4
    for (int g = 0; g < 64; g++)
        acc += sc[g] * wsc[WS_PCTX + ((long)b*64 + g)*1024 + h];
    float ctx = acc * invL;
    out[OUT_CTX + (long)b*NH + h] = ctx;
    ((unsigned short*)(ws + WS_LA))[(long)b*2048 + 1024 + h] = f2bf(ctx);
    int s = q*256 + t;
    float e = wsc[WS_E + (long)b*NS + s];
    out[OUT_ATTN + (long)b*NS + s] = expf(e - M)*invL;
}

// ---------------- logits via MFMA, split-K2, tile-blocked partials ----------------
// partial layout: P[half][vt][r*16 + c]  (r = batch row 0..63, c = vocab col 0..15)
__global__ void __launch_bounds__(256) k_logits_mfma(const float* __restrict__ oW,
                                                     const float* __restrict__ wsc,
                                                     float* __restrict__ ws) {
    int wave = blockIdx.x*4 + (threadIdx.x >> 6);   // 4000 waves (1000 blocks)
    int lane = threadIdx.x & 63;
    int half = wave & 1, vt = wave >> 1;
    int v0 = vt * 16, kbase = half * 1024;
    int col = lane & 15, kg = lane >> 4;
    const unsigned short* LA = (const unsigned short*)(wsc + WS_LA);
    const float* wrow = oW + (long)(v0 + col)*2048 + kbase + kg*8;
    f32x4 acc[4];
    #pragma unroll
    for (int m = 0; m < 4; m++) acc[m] = (f32x4){0.f,0.f,0.f,0.f};
    #pragma unroll 4
    for (int k0 = 0; k0 < 1024; k0 += 32) {
        float4 wa = *(const float4*)(wrow + k0);
        float4 wb = *(const float4*)(wrow + k0 + 4);
        bf16x8 bf = cvt8(wa, wb);
        #pragma unroll
        for (int m = 0; m < 4; m++) {
            bf16x8 af = *(const bf16x8*)(LA + (long)(m*16 + col)*2048 + kbase + k0 + kg*8);
            acc[m] = __builtin_amdgcn_mfma_f32_16x16x32_bf16(af, bf, acc[m], 0, 0, 0);
        }
    }
    float* P = ws + WS_P + ((long)half*2000 + vt)*1024;
    #pragma unroll
    for (int m = 0; m < 4; m++)
        #pragma unroll
        for (int j = 0; j < 4; j++)
            P[(m*16 + kg*4 + j)*16 + col] = acc[m][j];
}

// ---------------- fused: K2-sum + bias + write logits (online max/sum), then normalize ----------------
__global__ void __launch_bounds__(1024) k_logsoftmax(const float* __restrict__ wsc,
                                                     const float* __restrict__ ob,
                                                     float* __restrict__ out) {
    int b = blockIdx.x, t = threadIdx.x;  // 64 x 1024
    __shared__ float red[1024];
    float* row = out + (long)b*NV;
    float m = -1e30f, l = 0.f;
    for (int vt = t; vt < 2000; vt += 1024) {
        const float* p0 = wsc + WS_P + (long)vt*1024 + b*16;
        const float* p1 = p0 + 2000L*1024;
        const float* bb = ob + vt*16;
        float* orow = row + vt*16;
        float vmax = -1e30f;
        float4 vs[4];
        #pragma unroll
        for (int qq = 0; qq < 4; qq++) {
            float4 a = *(const float4*)(p0 + qq*4);
            float4 c = *(const float4*)(p1 + qq*4);
            float4 bbv = *(const float4*)(bb + qq*4);
            float4 v = make_float4(a.x+c.x+bbv.x, a.y+c.y+bbv.y, a.z+c.z+bbv.z, a.w+c.w+bbv.w);
            *(float4*)(orow + qq*4) = v;
            vs[qq] = v;
            vmax = fmaxf(vmax, fmaxf(fmaxf(v.x, v.y), fmaxf(v.z, v.w)));
        }
        float mnew = fmaxf(m, vmax);
        float coef = expf(m - mnew);
        float ls = 0.f;
        #pragma unroll
        for (int qq = 0; qq < 4; qq++) {
            ls += expf(vs[qq].x - mnew) + expf(vs[qq].y - mnew)
                + expf(vs[qq].z - mnew) + expf(vs[qq].w - mnew);
        }
        l = l*coef + ls;
        m = mnew;
    }
    red[t] = m; __syncthreads();
    for (int o = 512; o > 0; o >>= 1) { if (t < o) red[t] = fmaxf(red[t], red[t+o]); __syncthreads(); }
    float M = red[0]; __syncthreads();
    red[t] = l * expf(m - M); __syncthreads();
    for (int o = 512; o > 0; o >>= 1) { if (t < o) red[t] += red[t+o]; __syncthreads(); }
    float lse = M + logf(red[0]);
    for (int i = t*4; i < NV; i += 4096) {
        float4 v = *(const float4*)(row + i);
        *(float4*)(row + i) = make_float4(v.x-lse, v.y-lse, v.z-lse, v.w-lse);
    }
}

extern "C" void kernel_launch(void* const* d_in, const int* in_sizes, int n_in,
                              void* d_out, int out_size, void* d_ws, size_t ws_size,
                              hipStream_t stream) {
    const int*   wi   = (const int*)d_in[0];
    const float* lctx = (const float*)d_in[1];
    const float* lhid = (const float*)d_in[2];
    const float* enc  = (const float*)d_in[3];
    const float* emb  = (const float*)d_in[4];
    const float* w_ih = (const float*)d_in[5];
    const float* w_hh = (const float*)d_in[6];
    const float* b_ih = (const float*)d_in[7];
    const float* b_hh = (const float*)d_in[8];
    const float* oW   = (const float*)d_in[9];
    const float* ob   = (const float*)d_in[10];
    float* out = (float*)d_out;
    float* ws  = (float*)d_ws;

    hipLaunchKernelGGL(k_prep,        dim3(64),   dim3(256),  0, stream, wi, lctx, lhid, emb, ws);
    hipLaunchKernelGGL(k_gru_mfma,    dim3(576),  dim3(256),  0, stream, w_ih, w_hh, ws);
    hipLaunchKernelGGL(k_gates,       dim3(256),  dim3(256),  0, stream, ws, b_ih, b_hh, lhid, out, ws);
    hipLaunchKernelGGL(k_attn,        dim3(1024), dim3(256),  0, stream, enc, out, ws);
    hipLaunchKernelGGL(k_attn_reduce, dim3(256),  dim3(256),  0, stream, ws, out, ws);
    hipLaunchKernelGGL(k_logits_mfma, dim3(1000), dim3(256),  0, stream, oW, ws, ws);
    hipLaunchKernelGGL(k_logsoftmax,  dim3(64),   dim3(1024), 0, stream, ws, ob, out);
}

// Round 6
// 219.031 us; speedup vs baseline: 1.1754x; 1.0788x over previous
//
#include <hip/hip_runtime.h>
#include <math.h>

#define NV 32000
#define NE 1024
#define NH 1024
#define NS 1024
#define NB 64

typedef __attribute__((ext_vector_type(4))) float f32x4;
typedef __attribute__((ext_vector_type(8))) short bf16x8;

// d_out layout (floats): output(B,V) | context(B,H) | hidden(1,B,H) | attn(B,1,S)
#define OUT_CTX   (NB*NV)
#define OUT_HID   (NB*NV + NB*NH)
#define OUT_ATTN  (NB*NV + 2*NB*NH)

// workspace layout (float offsets)
#define WS_XA   0                          // ushort[64][2048] x0 bf16
#define WS_HA   (WS_XA + 65536)            // ushort[64][1024] h_prev bf16
#define WS_PG   (WS_HA + 32768)            // f32 [12][3072][64] GRU partials
#define WS_E    (WS_PG + 12*3072*64)       // f32 [64][1024] raw energies
#define WS_PCTX (WS_E + NB*NS)             // f32 [64][64][1024] attn ctx partials (b, g, h)
#define WS_ML   (WS_PCTX + 64*64*1024)     // f32 [64][64][2]  (m, l) per (b, g)
#define WS_LA   (WS_ML + 8192)             // ushort[64][2048] concat(h,ctx) bf16
#define WS_ML2  (WS_LA + 65536)            // f32 [64][2048][2] logits chunk (m,l) per (row, vt)
#define WS_LSE  (WS_ML2 + 64*2048*2)       // f32 [64] lse per row

__device__ inline unsigned short f2bf(float f) {
    unsigned u = __builtin_bit_cast(unsigned, f);
    u += 0x7fffu + ((u >> 16) & 1u);   // RNE
    return (unsigned short)(u >> 16);
}

__device__ inline bf16x8 cvt8(float4 a, float4 b) {
    bf16x8 r;
    r[0] = (short)f2bf(a.x); r[1] = (short)f2bf(a.y);
    r[2] = (short)f2bf(a.z); r[3] = (short)f2bf(a.w);
    r[4] = (short)f2bf(b.x); r[5] = (short)f2bf(b.y);
    r[6] = (short)f2bf(b.z); r[7] = (short)f2bf(b.w);
    return r;
}

__device__ inline void store_bf4(unsigned short* p, float4 v) {
    ushort4 u = make_ushort4(f2bf(v.x), f2bf(v.y), f2bf(v.z), f2bf(v.w));
    *(ushort4*)p = u;
}

// ---------------- prep: x0 = concat(emb, lctx) -> bf16; h_prev -> bf16 ----------------
__global__ void k_prep(const int* __restrict__ wi, const float* __restrict__ lctx,
                       const float* __restrict__ lhid, const float* __restrict__ emb,
                       float* __restrict__ ws) {
    int b = blockIdx.x, t = threadIdx.x;           // 64 x 256
    unsigned short* XA = (unsigned short*)(ws + WS_XA);
    unsigned short* HA = (unsigned short*)(ws + WS_HA);
    long row = wi[b];
    float4 e4 = ((const float4*)(emb + row*NE))[t];
    float4 c4 = ((const float4*)(lctx + (long)b*NH))[t];
    float4 h4 = ((const float4*)(lhid + (long)b*NH))[t];
    store_bf4(XA + (long)b*2048 + t*4,        e4);
    store_bf4(XA + (long)b*2048 + 1024 + t*4, c4);
    store_bf4(HA + (long)b*1024 + t*4,        h4);
}

// ---------------- GRU GEMM via MFMA: partials [12][3072][64], K-chunks of 256 ----------------
__global__ void __launch_bounds__(256) k_gru_mfma(const float* __restrict__ w_ih,
                                                  const float* __restrict__ w_hh,
                                                  float* __restrict__ ws) {
    int wave = blockIdx.x*4 + (threadIdx.x >> 6);   // 2304 waves (576 blocks)
    int lane = threadIdx.x & 63;
    int c = wave % 12, ntile = wave / 12;           // 192 n-tiles
    int n0 = ntile * 16;
    int col = lane & 15, kg = lane >> 4;
    const unsigned short* XA = (const unsigned short*)(ws + WS_XA);
    const unsigned short* HA = (const unsigned short*)(ws + WS_HA);
    const float* Wp; const unsigned short* Ap; int ld, kbase;
    if (c < 8) { Wp = w_ih; Ap = XA; ld = 2048; kbase = c*256; }
    else       { Wp = w_hh; Ap = HA; ld = 1024; kbase = (c-8)*256; }
    const float* wrow = Wp + (long)(n0 + col)*ld + kbase + kg*8;
    f32x4 acc[4];
    #pragma unroll
    for (int m = 0; m < 4; m++) acc[m] = (f32x4){0.f,0.f,0.f,0.f};
    #pragma unroll 4
    for (int k0 = 0; k0 < 256; k0 += 32) {
        float4 wa = *(const float4*)(wrow + k0);
        float4 wb = *(const float4*)(wrow + k0 + 4);
        bf16x8 bf = cvt8(wa, wb);
        #pragma unroll
        for (int m = 0; m < 4; m++) {
            bf16x8 af = *(const bf16x8*)(Ap + (long)(m*16 + col)*ld + kbase + k0 + kg*8);
            acc[m] = __builtin_amdgcn_mfma_f32_16x16x32_bf16(af, bf, acc[m], 0, 0, 0);
        }
    }
    float* pg = ws + WS_PG + ((long)c*3072 + n0 + col)*64;
    #pragma unroll
    for (int m = 0; m < 4; m++)
        #pragma unroll
        for (int j = 0; j < 4; j++)
            pg[m*16 + kg*4 + j] = acc[m][j];
}

// ---------------- GRU gates ----------------
__global__ void k_gates(const float* __restrict__ wsc, const float* __restrict__ b_ih,
                        const float* __restrict__ b_hh, const float* __restrict__ lhid,
                        float* __restrict__ out, float* __restrict__ ws) {
    int g = blockIdx.x*256 + threadIdx.x;  // 65536 threads
    int b = g & 63, i = g >> 6;
    float gir=0.f, giz=0.f, gin=0.f, ghr=0.f, ghz=0.f, ghn=0.f;
    #pragma unroll
    for (int c = 0; c < 8; c++) {
        long base = WS_PG + (long)c*3072*64;
        gir += wsc[base + ((long)(0*NH + i))*64 + b];
        giz += wsc[base + ((long)(1*NH + i))*64 + b];
        gin += wsc[base + ((long)(2*NH + i))*64 + b];
    }
    #pragma unroll
    for (int c = 8; c < 12; c++) {
        long base = WS_PG + (long)c*3072*64;
        ghr += wsc[base + ((long)(0*NH + i))*64 + b];
        ghz += wsc[base + ((long)(1*NH + i))*64 + b];
        ghn += wsc[base + ((long)(2*NH + i))*64 + b];
    }
    gir += b_ih[i];        ghr += b_hh[i];
    giz += b_ih[NH + i];   ghz += b_hh[NH + i];
    gin += b_ih[2*NH + i]; ghn += b_hh[2*NH + i];
    float r = 1.f / (1.f + expf(-(gir + ghr)));
    float z = 1.f / (1.f + expf(-(giz + ghz)));
    float n = tanhf(gin + r*ghn);
    float hp = lhid[(long)b*NH + i];
    float h = (1.f - z)*n + z*hp;
    out[OUT_HID + (long)b*NH + i] = h;
    ((unsigned short*)(ws + WS_LA))[(long)b*2048 + i] = f2bf(h);
}

// ---------------- fused attention: single encoder pass, online softmax ----------------
__global__ void __launch_bounds__(256) k_attn(const float* __restrict__ enc,
                                              const float* __restrict__ out,
                                              float* __restrict__ ws) {
    int widx = threadIdx.x >> 6, lane = threadIdx.x & 63;
    int b = blockIdx.x >> 4;                 // 1024 blocks
    int g = (blockIdx.x & 15)*4 + widx;      // 0..63
    const float4* hr = (const float4*)(out + OUT_HID + (long)b*NH);
    float4 h0 = hr[lane], h1 = hr[64+lane], h2 = hr[128+lane], h3 = hr[192+lane];
    float m = -1e30f, l = 0.f;
    float4 c0 = make_float4(0,0,0,0), c1 = c0, c2 = c0, c3 = c0;
    const float4* vp = (const float4*)(enc + ((long)(g*16)*NB + b)*NH);
    const long sstr = (long)NB*NH/4;         // float4 stride between s
    float4 a0 = vp[lane], a1 = vp[64+lane], a2 = vp[128+lane], a3 = vp[192+lane];
    #pragma unroll
    for (int si = 0; si < 16; si++) {
        float4 n0 = a0, n1 = a1, n2 = a2, n3 = a3;
        if (si < 15) {
            const float4* np = vp + (long)(si+1)*sstr;
            n0 = np[lane]; n1 = np[64+lane]; n2 = np[128+lane]; n3 = np[192+lane];
        }
        float d = a0.x*h0.x + a0.y*h0.y + a0.z*h0.z + a0.w*h0.w
                + a1.x*h1.x + a1.y*h1.y + a1.z*h1.z + a1.w*h1.w
                + a2.x*h2.x + a2.y*h2.y + a2.z*h2.z + a2.w*h2.w
                + a3.x*h3.x + a3.y*h3.y + a3.z*h3.z + a3.w*h3.w;
        #pragma unroll
        for (int o = 32; o > 0; o >>= 1) d += __shfl_xor(d, o);
        if (lane == 0) ws[WS_E + (long)b*NS + g*16 + si] = d;
        float mnew = fmaxf(m, d);
        float coef = expf(m - mnew);
        float p = expf(d - mnew);
        l = l*coef + p;
        c0.x = c0.x*coef + p*a0.x; c0.y = c0.y*coef + p*a0.y;
        c0.z = c0.z*coef + p*a0.z; c0.w = c0.w*coef + p*a0.w;
        c1.x = c1.x*coef + p*a1.x; c1.y = c1.y*coef + p*a1.y;
        c1.z = c1.z*coef + p*a1.z; c1.w = c1.w*coef + p*a1.w;
        c2.x = c2.x*coef + p*a2.x; c2.y = c2.y*coef + p*a2.y;
        c2.z = c2.z*coef + p*a2.z; c2.w = c2.w*coef + p*a2.w;
        c3.x = c3.x*coef + p*a3.x; c3.y = c3.y*coef + p*a3.y;
        c3.z = c3.z*coef + p*a3.z; c3.w = c3.w*coef + p*a3.w;
        m = mnew;
        a0 = n0; a1 = n1; a2 = n2; a3 = n3;
    }
    float* pc = ws + WS_PCTX + ((long)b*64 + g)*1024;
    *(float4*)(pc + 0*256 + lane*4) = c0;
    *(float4*)(pc + 1*256 + lane*4) = c1;
    *(float4*)(pc + 2*256 + lane*4) = c2;
    *(float4*)(pc + 3*256 + lane*4) = c3;
    if (lane == 0) {
        ws[WS_ML + ((long)b*64 + g)*2]     = m;
        ws[WS_ML + ((long)b*64 + g)*2 + 1] = l;
    }
}

// ---------------- attn reduce (wide): 256 blocks = (b, quarter) ----------------
__global__ void k_attn_reduce(const float* __restrict__ wsc, float* __restrict__ out,
                              float* __restrict__ ws) {
    int b = blockIdx.x >> 2, q = blockIdx.x & 3;   // 256 blocks x 256 threads
    int t = threadIdx.x;
    __shared__ float sm[64], sl[64], sc[64];
    __shared__ float sM, sinvL;
    if (t < 64) {
        sm[t] = wsc[WS_ML + ((long)b*64 + t)*2];
        sl[t] = wsc[WS_ML + ((long)b*64 + t)*2 + 1];
    }
    __syncthreads();
    if (t == 0) {
        float M = -1e30f;
        for (int g = 0; g < 64; g++) M = fmaxf(M, sm[g]);
        float L = 0.f;
        for (int g = 0; g < 64; g++) L += sl[g]*expf(sm[g] - M);
        sM = M; sinvL = 1.f/L;
    }
    __syncthreads();
    float M = sM, invL = sinvL;
    if (t < 64) sc[t] = expf(sm[t] - M);
    __syncthreads();
    int h = q*256 + t;
    float acc = 0.f;
    #pragma unroll 8
    for (int g = 0; g < 64; g++)
        acc += sc[g] * wsc[WS_PCTX + ((long)b*64 + g)*1024 + h];
    float ctx = acc * invL;
    out[OUT_CTX + (long)b*NH + h] = ctx;
    ((unsigned short*)(ws + WS_LA))[(long)b*2048 + 1024 + h] = f2bf(ctx);
    int s = q*256 + t;
    float e = wsc[WS_E + (long)b*NS + s];
    out[OUT_ATTN + (long)b*NS + s] = expf(e - M)*invL;
}

// ---------------- logits via MFMA, single-K, direct write + chunk (m,l) ----------------
// 2000 blocks x 64 threads (1 wave). Writes logits+bias directly to out,
// and per-16-col-tile (max, sumexp) to ws [row][2048][2].
__global__ void __launch_bounds__(64) k_logits_mfma(const float* __restrict__ oW,
                                                    const float* __restrict__ ob,
                                                    const float* __restrict__ wsc,
                                                    float* __restrict__ out,
                                                    float* __restrict__ ws) {
    int vt = blockIdx.x;                    // 0..1999
    int lane = threadIdx.x & 63;
    int v0 = vt * 16;
    int col = lane & 15, kg = lane >> 4;
    const unsigned short* LA = (const unsigned short*)(wsc + WS_LA);
    const float* wrow = oW + (long)(v0 + col)*2048 + kg*8;
    f32x4 acc[4];
    #pragma unroll
    for (int m = 0; m < 4; m++) acc[m] = (f32x4){0.f,0.f,0.f,0.f};
    #pragma unroll 4
    for (int k0 = 0; k0 < 2048; k0 += 32) {
        float4 wa = *(const float4*)(wrow + k0);
        float4 wb = *(const float4*)(wrow + k0 + 4);
        bf16x8 bf = cvt8(wa, wb);
        #pragma unroll
        for (int m = 0; m < 4; m++) {
            bf16x8 af = *(const bf16x8*)(LA + (long)(m*16 + col)*2048 + k0 + kg*8);
            acc[m] = __builtin_amdgcn_mfma_f32_16x16x32_bf16(af, bf, acc[m], 0, 0, 0);
        }
    }
    float bias = ob[v0 + col];
    #pragma unroll
    for (int m = 0; m < 4; m++) {
        #pragma unroll
        for (int j = 0; j < 4; j++) {
            int row = m*16 + kg*4 + j;
            float v = acc[m][j] + bias;
            out[(long)row*NV + v0 + col] = v;
            // row-max over the 16 col-lanes (xor within bits 0..3 keeps kg)
            float mx = v;
            mx = fmaxf(mx, __shfl_xor(mx, 1));
            mx = fmaxf(mx, __shfl_xor(mx, 2));
            mx = fmaxf(mx, __shfl_xor(mx, 4));
            mx = fmaxf(mx, __shfl_xor(mx, 8));
            float p = expf(v - mx);
            p += __shfl_xor(p, 1);
            p += __shfl_xor(p, 2);
            p += __shfl_xor(p, 4);
            p += __shfl_xor(p, 8);
            if (col == 0)
                *(float2*)(ws + WS_ML2 + ((long)row*2048 + vt)*2) = make_float2(mx, p);
        }
    }
}

// ---------------- lse per row: reduce 2000 chunk (m,l) pairs ----------------
__global__ void __launch_bounds__(1024) k_lse(const float* __restrict__ wsc,
                                              float* __restrict__ ws) {
    int b = blockIdx.x, t = threadIdx.x;    // 64 x 1024
    __shared__ float sm_[1024], sl_[1024];
    const float2* ml = (const float2*)(wsc + WS_ML2 + (long)b*4096);
    float m = -1e30f, l = 0.f;
    for (int c = t; c < 2000; c += 1024) {
        float2 v = ml[c];
        float mn = fmaxf(m, v.x);
        l = l*expf(m - mn) + v.y*expf(v.x - mn);
        m = mn;
    }
    sm_[t] = m; sl_[t] = l; __syncthreads();
    for (int o = 512; o > 0; o >>= 1) {
        if (t < o) {
            float m2 = sm_[t+o], l2 = sl_[t+o];
            float mn = fmaxf(sm_[t], m2);
            sl_[t] = sl_[t]*expf(sm_[t] - mn) + l2*expf(m2 - mn);
            sm_[t] = mn;
        }
        __syncthreads();
    }
    if (t == 0) ws[WS_LSE + b] = sm_[0] + logf(sl_[0]);
}

// ---------------- normalize logits: full grid ----------------
__global__ void __launch_bounds__(1024) k_norm(const float* __restrict__ wsc,
                                               float* __restrict__ out) {
    int g = blockIdx.x*1024 + threadIdx.x;  // 500 x 1024 = 512000 = 64 x 8000
    int b = g / 8000;
    int i = g - b*8000;
    float lse = wsc[WS_LSE + b];
    float4* p = (float4*)(out + (long)b*NV) + i;
    float4 v = *p;
    *p = make_float4(v.x-lse, v.y-lse, v.z-lse, v.w-lse);
}

extern "C" void kernel_launch(void* const* d_in, const int* in_sizes, int n_in,
                              void* d_out, int out_size, void* d_ws, size_t ws_size,
                              hipStream_t stream) {
    const int*   wi   = (const int*)d_in[0];
    const float* lctx = (const float*)d_in[1];
    const float* lhid = (const float*)d_in[2];
    const float* enc  = (const float*)d_in[3];
    const float* emb  = (const float*)d_in[4];
    const float* w_ih = (const float*)d_in[5];
    const float* w_hh = (const float*)d_in[6];
    const float* b_ih = (const float*)d_in[7];
    const float* b_hh = (const float*)d_in[8];
    const float* oW   = (const float*)d_in[9];
    const float* ob   = (const float*)d_in[10];
    float* out = (float*)d_out;
    float* ws  = (float*)d_ws;

    hipLaunchKernelGGL(k_prep,        dim3(64),   dim3(256),  0, stream, wi, lctx, lhid, emb, ws);
    hipLaunchKernelGGL(k_gru_mfma,    dim3(576),  dim3(256),  0, stream, w_ih, w_hh, ws);
    hipLaunchKernelGGL(k_gates,       dim3(256),  dim3(256),  0, stream, ws, b_ih, b_hh, lhid, out, ws);
    hipLaunchKernelGGL(k_attn,        dim3(1024), dim3(256),  0, stream, enc, out, ws);
    hipLaunchKernelGGL(k_attn_reduce, dim3(256),  dim3(256),  0, stream, ws, out, ws);
    hipLaunchKernelGGL(k_logits_mfma, dim3(2000), dim3(64),   0, stream, oW, ob, ws, out, ws);
    hipLaunchKernelGGL(k_lse,         dim3(64),   dim3(1024), 0, stream, ws, ws);
    hipLaunchKernelGGL(k_norm,        dim3(500),  dim3(1024), 0, stream, ws, out);
}

// Round 7
// 213.051 us; speedup vs baseline: 1.2084x; 1.0281x over previous
//
#include <hip/hip_runtime.h>
#include <math.h>

#define NV 32000
#define NE 1024
#define NH 1024
#define NS 1024
#define NB 64

typedef __attribute__((ext_vector_type(4))) float f32x4;
typedef __attribute__((ext_vector_type(8))) short bf16x8;

// d_out layout (floats): output(B,V) | context(B,H) | hidden(1,B,H) | attn(B,1,S)
#define OUT_CTX   (NB*NV)
#define OUT_HID   (NB*NV + NB*NH)
#define OUT_ATTN  (NB*NV + 2*NB*NH)

// workspace layout (float offsets)
#define WS_XA   0                          // ushort[64][2048] x0 bf16
#define WS_HA   (WS_XA + 65536)            // ushort[64][1024] h_prev bf16
#define WS_PG   (WS_HA + 32768)            // f32 [12][3072][64] GRU partials
#define WS_E    (WS_PG + 12*3072*64)       // f32 [64][1024] raw energies
#define WS_PCTX (WS_E + NB*NS)             // f32 [64][64][1024] attn ctx partials (b, g, h)
#define WS_ML   (WS_PCTX + 64*64*1024)     // f32 [64][64][2]  (m, l) per (b, g)
#define WS_LA   (WS_ML + 8192)             // ushort[64][2048] concat(h,ctx) bf16
#define WS_ML2  (WS_LA + 65536)            // f32 [64][2048][2] logits chunk (m,l) per (row, vt)
#define WS_LSE  (WS_ML2 + 64*2048*2)       // f32 [64] lse per row
#define WS_P    (WS_LSE + 64)              // f32 [2000][1024] logits h-half partials, tile-blocked

__device__ inline unsigned short f2bf(float f) {
    unsigned u = __builtin_bit_cast(unsigned, f);
    u += 0x7fffu + ((u >> 16) & 1u);   // RNE
    return (unsigned short)(u >> 16);
}

__device__ inline bf16x8 cvt8(float4 a, float4 b) {
    bf16x8 r;
    r[0] = (short)f2bf(a.x); r[1] = (short)f2bf(a.y);
    r[2] = (short)f2bf(a.z); r[3] = (short)f2bf(a.w);
    r[4] = (short)f2bf(b.x); r[5] = (short)f2bf(b.y);
    r[6] = (short)f2bf(b.z); r[7] = (short)f2bf(b.w);
    return r;
}

__device__ inline void store_bf4(unsigned short* p, float4 v) {
    ushort4 u = make_ushort4(f2bf(v.x), f2bf(v.y), f2bf(v.z), f2bf(v.w));
    *(ushort4*)p = u;
}

// ---------------- prep: x0 = concat(emb, lctx) -> bf16; h_prev -> bf16 ----------------
__global__ void k_prep(const int* __restrict__ wi, const float* __restrict__ lctx,
                       const float* __restrict__ lhid, const float* __restrict__ emb,
                       float* __restrict__ ws) {
    int b = blockIdx.x, t = threadIdx.x;           // 64 x 256
    unsigned short* XA = (unsigned short*)(ws + WS_XA);
    unsigned short* HA = (unsigned short*)(ws + WS_HA);
    long row = wi[b];
    float4 e4 = ((const float4*)(emb + row*NE))[t];
    float4 c4 = ((const float4*)(lctx + (long)b*NH))[t];
    float4 h4 = ((const float4*)(lhid + (long)b*NH))[t];
    store_bf4(XA + (long)b*2048 + t*4,        e4);
    store_bf4(XA + (long)b*2048 + 1024 + t*4, c4);
    store_bf4(HA + (long)b*1024 + t*4,        h4);
}

// ---------------- GRU GEMM via MFMA: partials [12][3072][64], K-chunks of 256 ----------------
__global__ void __launch_bounds__(256) k_gru_mfma(const float* __restrict__ w_ih,
                                                  const float* __restrict__ w_hh,
                                                  float* __restrict__ ws) {
    int wave = blockIdx.x*4 + (threadIdx.x >> 6);   // 2304 waves (576 blocks)
    int lane = threadIdx.x & 63;
    int c = wave % 12, ntile = wave / 12;           // 192 n-tiles
    int n0 = ntile * 16;
    int col = lane & 15, kg = lane >> 4;
    const unsigned short* XA = (const unsigned short*)(ws + WS_XA);
    const unsigned short* HA = (const unsigned short*)(ws + WS_HA);
    const float* Wp; const unsigned short* Ap; int ld, kbase;
    if (c < 8) { Wp = w_ih; Ap = XA; ld = 2048; kbase = c*256; }
    else       { Wp = w_hh; Ap = HA; ld = 1024; kbase = (c-8)*256; }
    const float* wrow = Wp + (long)(n0 + col)*ld + kbase + kg*8;
    f32x4 acc[4];
    #pragma unroll
    for (int m = 0; m < 4; m++) acc[m] = (f32x4){0.f,0.f,0.f,0.f};
    #pragma unroll 4
    for (int k0 = 0; k0 < 256; k0 += 32) {
        float4 wa = *(const float4*)(wrow + k0);
        float4 wb = *(const float4*)(wrow + k0 + 4);
        bf16x8 bf = cvt8(wa, wb);
        #pragma unroll
        for (int m = 0; m < 4; m++) {
            bf16x8 af = *(const bf16x8*)(Ap + (long)(m*16 + col)*ld + kbase + k0 + kg*8);
            acc[m] = __builtin_amdgcn_mfma_f32_16x16x32_bf16(af, bf, acc[m], 0, 0, 0);
        }
    }
    float* pg = ws + WS_PG + ((long)c*3072 + n0 + col)*64;
    #pragma unroll
    for (int m = 0; m < 4; m++)
        #pragma unroll
        for (int j = 0; j < 4; j++)
            pg[m*16 + kg*4 + j] = acc[m][j];
}

// ---------------- GRU gates ----------------
__global__ void k_gates(const float* __restrict__ wsc, const float* __restrict__ b_ih,
                        const float* __restrict__ b_hh, const float* __restrict__ lhid,
                        float* __restrict__ out, float* __restrict__ ws) {
    int g = blockIdx.x*256 + threadIdx.x;  // 65536 threads
    int b = g & 63, i = g >> 6;
    float gir=0.f, giz=0.f, gin=0.f, ghr=0.f, ghz=0.f, ghn=0.f;
    #pragma unroll
    for (int c = 0; c < 8; c++) {
        long base = WS_PG + (long)c*3072*64;
        gir += wsc[base + ((long)(0*NH + i))*64 + b];
        giz += wsc[base + ((long)(1*NH + i))*64 + b];
        gin += wsc[base + ((long)(2*NH + i))*64 + b];
    }
    #pragma unroll
    for (int c = 8; c < 12; c++) {
        long base = WS_PG + (long)c*3072*64;
        ghr += wsc[base + ((long)(0*NH + i))*64 + b];
        ghz += wsc[base + ((long)(1*NH + i))*64 + b];
        ghn += wsc[base + ((long)(2*NH + i))*64 + b];
    }
    gir += b_ih[i];        ghr += b_hh[i];
    giz += b_ih[NH + i];   ghz += b_hh[NH + i];
    gin += b_ih[2*NH + i]; ghn += b_hh[2*NH + i];
    float r = 1.f / (1.f + expf(-(gir + ghr)));
    float z = 1.f / (1.f + expf(-(giz + ghz)));
    float n = tanhf(gin + r*ghn);
    float hp = lhid[(long)b*NH + i];
    float h = (1.f - z)*n + z*hp;
    out[OUT_HID + (long)b*NH + i] = h;
    ((unsigned short*)(ws + WS_LA))[(long)b*2048 + i] = f2bf(h);
}

// ---------------- fused: attention pass + logits h-half GEMM (independent streams) ----------------
// blocks [0,500): logits h-half, 4 waves x 1 vocab-tile each -> partials WS_P
// blocks [500,1524): attention with defer-max online softmax
__global__ void __launch_bounds__(256) k_attn_logh(const float* __restrict__ enc,
                                                   const float* __restrict__ oW,
                                                   const float* __restrict__ out,
                                                   float* __restrict__ ws) {
    int widx = threadIdx.x >> 6, lane = threadIdx.x & 63;
    if (blockIdx.x < 500) {
        // ---- logits h-half: vt = blockIdx.x*4 + widx, K = 0..1023 ----
        int vt = blockIdx.x*4 + widx;
        int v0 = vt * 16;
        int col = lane & 15, kg = lane >> 4;
        const unsigned short* LA = (const unsigned short*)(ws + WS_LA);
        const float* wrow = oW + (long)(v0 + col)*2048 + kg*8;
        f32x4 acc[4];
        #pragma unroll
        for (int m = 0; m < 4; m++) acc[m] = (f32x4){0.f,0.f,0.f,0.f};
        #pragma unroll 4
        for (int k0 = 0; k0 < 1024; k0 += 32) {
            float4 wa = *(const float4*)(wrow + k0);
            float4 wb = *(const float4*)(wrow + k0 + 4);
            bf16x8 bf = cvt8(wa, wb);
            #pragma unroll
            for (int m = 0; m < 4; m++) {
                bf16x8 af = *(const bf16x8*)(LA + (long)(m*16 + col)*2048 + k0 + kg*8);
                acc[m] = __builtin_amdgcn_mfma_f32_16x16x32_bf16(af, bf, acc[m], 0, 0, 0);
            }
        }
        float* P = ws + WS_P + (long)vt*1024;
        #pragma unroll
        for (int m = 0; m < 4; m++)
            #pragma unroll
            for (int j = 0; j < 4; j++)
                P[(m*16 + kg*4 + j)*16 + col] = acc[m][j];
        return;
    }
    // ---- attention: b, g from remaining 1024 blocks ----
    int blk = blockIdx.x - 500;
    int b = blk >> 4;
    int g = (blk & 15)*4 + widx;             // 0..63
    const float4* hr = (const float4*)(out + OUT_HID + (long)b*NH);
    float4 h0 = hr[lane], h1 = hr[64+lane], h2 = hr[128+lane], h3 = hr[192+lane];
    float m = -1e30f, l = 0.f;
    float4 c0 = make_float4(0,0,0,0), c1 = c0, c2 = c0, c3 = c0;
    const float4* vp = (const float4*)(enc + ((long)(g*16)*NB + b)*NH);
    const long sstr = (long)NB*NH/4;         // float4 stride between s
    float4 a0 = vp[lane], a1 = vp[64+lane], a2 = vp[128+lane], a3 = vp[192+lane];
    #pragma unroll
    for (int si = 0; si < 16; si++) {
        float4 n0 = a0, n1 = a1, n2 = a2, n3 = a3;
        if (si < 15) {
            const float4* np = vp + (long)(si+1)*sstr;
            n0 = np[lane]; n1 = np[64+lane]; n2 = np[128+lane]; n3 = np[192+lane];
        }
        float d = a0.x*h0.x + a0.y*h0.y + a0.z*h0.z + a0.w*h0.w
                + a1.x*h1.x + a1.y*h1.y + a1.z*h1.z + a1.w*h1.w
                + a2.x*h2.x + a2.y*h2.y + a2.z*h2.z + a2.w*h2.w
                + a3.x*h3.x + a3.y*h3.y + a3.z*h3.z + a3.w*h3.w;
        #pragma unroll
        for (int o = 32; o > 0; o >>= 1) d += __shfl_xor(d, o);
        if (lane == 0) ws[WS_E + (long)b*NS + g*16 + si] = d;
        // defer-max: rescale only when d exceeds running max by > 8 (wave-uniform branch)
        if (d > m + 8.f) {
            float coef = expf(m - d);       // m=-1e30 first time -> coef = 0
            l *= coef;
            c0.x *= coef; c0.y *= coef; c0.z *= coef; c0.w *= coef;
            c1.x *= coef; c1.y *= coef; c1.z *= coef; c1.w *= coef;
            c2.x *= coef; c2.y *= coef; c2.z *= coef; c2.w *= coef;
            c3.x *= coef; c3.y *= coef; c3.z *= coef; c3.w *= coef;
            m = d;
        }
        float p = expf(d - m);               // bounded by e^8
        l += p;
        c0.x += p*a0.x; c0.y += p*a0.y; c0.z += p*a0.z; c0.w += p*a0.w;
        c1.x += p*a1.x; c1.y += p*a1.y; c1.z += p*a1.z; c1.w += p*a1.w;
        c2.x += p*a2.x; c2.y += p*a2.y; c2.z += p*a2.z; c2.w += p*a2.w;
        c3.x += p*a3.x; c3.y += p*a3.y; c3.z += p*a3.z; c3.w += p*a3.w;
        a0 = n0; a1 = n1; a2 = n2; a3 = n3;
    }
    float* pc = ws + WS_PCTX + ((long)b*64 + g)*1024;
    *(float4*)(pc + 0*256 + lane*4) = c0;
    *(float4*)(pc + 1*256 + lane*4) = c1;
    *(float4*)(pc + 2*256 + lane*4) = c2;
    *(float4*)(pc + 3*256 + lane*4) = c3;
    if (lane == 0) {
        ws[WS_ML + ((long)b*64 + g)*2]     = m;
        ws[WS_ML + ((long)b*64 + g)*2 + 1] = l;
    }
}

// ---------------- attn reduce (wide): 256 blocks = (b, quarter) ----------------
__global__ void k_attn_reduce(const float* __restrict__ wsc, float* __restrict__ out,
                              float* __restrict__ ws) {
    int b = blockIdx.x >> 2, q = blockIdx.x & 3;   // 256 blocks x 256 threads
    int t = threadIdx.x;
    __shared__ float sm[64], sl[64], sc[64];
    __shared__ float sM, sinvL;
    if (t < 64) {
        sm[t] = wsc[WS_ML + ((long)b*64 + t)*2];
        sl[t] = wsc[WS_ML + ((long)b*64 + t)*2 + 1];
    }
    __syncthreads();
    if (t == 0) {
        float M = -1e30f;
        for (int g = 0; g < 64; g++) M = fmaxf(M, sm[g]);
        float L = 0.f;
        for (int g = 0; g < 64; g++) L += sl[g]*expf(sm[g] - M);
        sM = M; sinvL = 1.f/L;
    }
    __syncthreads();
    float M = sM, invL = sinvL;
    if (t < 64) sc[t] = expf(sm[t] - M);
    __syncthreads();
    int h = q*256 + t;
    float acc = 0.f;
    #pragma unroll 8
    for (int g = 0; g < 64; g++)
        acc += sc[g] * wsc[WS_PCTX + ((long)b*64 + g)*1024 + h];
    float ctx = acc * invL;
    out[OUT_CTX + (long)b*NH + h] = ctx;
    ((unsigned short*)(ws + WS_LA))[(long)b*2048 + 1024 + h] = f2bf(ctx);
    int s = q*256 + t;
    float e = wsc[WS_E + (long)b*NS + s];
    out[OUT_ATTN + (long)b*NS + s] = expf(e - M)*invL;
}

// ---------------- logits ctx-half + partial + bias -> out, chunk (m,l) ----------------
// 500 blocks x 4 waves, each wave one vocab-tile, K = 1024..2047
__global__ void __launch_bounds__(256) k_logits_ctx(const float* __restrict__ oW,
                                                    const float* __restrict__ ob,
                                                    const float* __restrict__ wsc,
                                                    float* __restrict__ out,
                                                    float* __restrict__ ws) {
    int widx = threadIdx.x >> 6, lane = threadIdx.x & 63;
    int vt = blockIdx.x*4 + widx;           // 0..1999
    int v0 = vt * 16;
    int col = lane & 15, kg = lane >> 4;
    const unsigned short* LA = (const unsigned short*)(wsc + WS_LA);
    const float* wrow = oW + (long)(v0 + col)*2048 + 1024 + kg*8;
    f32x4 acc[4];
    #pragma unroll
    for (int m = 0; m < 4; m++) acc[m] = (f32x4){0.f,0.f,0.f,0.f};
    #pragma unroll 4
    for (int k0 = 0; k0 < 1024; k0 += 32) {
        float4 wa = *(const float4*)(wrow + k0);
        float4 wb = *(const float4*)(wrow + k0 + 4);
        bf16x8 bf = cvt8(wa, wb);
        #pragma unroll
        for (int m = 0; m < 4; m++) {
            bf16x8 af = *(const bf16x8*)(LA + (long)(m*16 + col)*2048 + 1024 + k0 + kg*8);
            acc[m] = __builtin_amdgcn_mfma_f32_16x16x32_bf16(af, bf, acc[m], 0, 0, 0);
        }
    }
    const float* P = wsc + WS_P + (long)vt*1024;
    float bias = ob[v0 + col];
    #pragma unroll
    for (int m = 0; m < 4; m++) {
        #pragma unroll
        for (int j = 0; j < 4; j++) {
            int row = m*16 + kg*4 + j;
            float v = acc[m][j] + P[row*16 + col] + bias;
            out[(long)row*NV + v0 + col] = v;
            float mx = v;
            mx = fmaxf(mx, __shfl_xor(mx, 1));
            mx = fmaxf(mx, __shfl_xor(mx, 2));
            mx = fmaxf(mx, __shfl_xor(mx, 4));
            mx = fmaxf(mx, __shfl_xor(mx, 8));
            float p = expf(v - mx);
            p += __shfl_xor(p, 1);
            p += __shfl_xor(p, 2);
            p += __shfl_xor(p, 4);
            p += __shfl_xor(p, 8);
            if (col == 0)
                *(float2*)(ws + WS_ML2 + ((long)row*2048 + vt)*2) = make_float2(mx, p);
        }
    }
}

// ---------------- lse per row: reduce 2000 chunk (m,l) pairs ----------------
__global__ void __launch_bounds__(1024) k_lse(const float* __restrict__ wsc,
                                              float* __restrict__ ws) {
    int b = blockIdx.x, t = threadIdx.x;    // 64 x 1024
    __shared__ float sm_[1024], sl_[1024];
    const float2* ml = (const float2*)(wsc + WS_ML2 + (long)b*4096);
    float m = -1e30f, l = 0.f;
    for (int c = t; c < 2000; c += 1024) {
        float2 v = ml[c];
        float mn = fmaxf(m, v.x);
        l = l*expf(m - mn) + v.y*expf(v.x - mn);
        m = mn;
    }
    sm_[t] = m; sl_[t] = l; __syncthreads();
    for (int o = 512; o > 0; o >>= 1) {
        if (t < o) {
            float m2 = sm_[t+o], l2 = sl_[t+o];
            float mn = fmaxf(sm_[t], m2);
            sl_[t] = sl_[t]*expf(sm_[t] - mn) + l2*expf(m2 - mn);
            sm_[t] = mn;
        }
        __syncthreads();
    }
    if (t == 0) ws[WS_LSE + b] = sm_[0] + logf(sl_[0]);
}

// ---------------- normalize logits: full grid ----------------
__global__ void __launch_bounds__(1024) k_norm(const float* __restrict__ wsc,
                                               float* __restrict__ out) {
    int g = blockIdx.x*1024 + threadIdx.x;  // 500 x 1024 = 512000 = 64 x 8000
    int b = g / 8000;
    int i = g - b*8000;
    float lse = wsc[WS_LSE + b];
    float4* p = (float4*)(out + (long)b*NV) + i;
    float4 v = *p;
    *p = make_float4(v.x-lse, v.y-lse, v.z-lse, v.w-lse);
}

extern "C" void kernel_launch(void* const* d_in, const int* in_sizes, int n_in,
                              void* d_out, int out_size, void* d_ws, size_t ws_size,
                              hipStream_t stream) {
    const int*   wi   = (const int*)d_in[0];
    const float* lctx = (const float*)d_in[1];
    const float* lhid = (const float*)d_in[2];
    const float* enc  = (const float*)d_in[3];
    const float* emb  = (const float*)d_in[4];
    const float* w_ih = (const float*)d_in[5];
    const float* w_hh = (const float*)d_in[6];
    const float* b_ih = (const float*)d_in[7];
    const float* b_hh = (const float*)d_in[8];
    const float* oW   = (const float*)d_in[9];
    const float* ob   = (const float*)d_in[10];
    float* out = (float*)d_out;
    float* ws  = (float*)d_ws;

    hipLaunchKernelGGL(k_prep,        dim3(64),   dim3(256),  0, stream, wi, lctx, lhid, emb, ws);
    hipLaunchKernelGGL(k_gru_mfma,    dim3(576),  dim3(256),  0, stream, w_ih, w_hh, ws);
    hipLaunchKernelGGL(k_gates,       dim3(256),  dim3(256),  0, stream, ws, b_ih, b_hh, lhid, out, ws);
    hipLaunchKernelGGL(k_attn_logh,   dim3(1524), dim3(256),  0, stream, enc, oW, out, ws);
    hipLaunchKernelGGL(k_attn_reduce, dim3(256),  dim3(256),  0, stream, ws, out, ws);
    hipLaunchKernelGGL(k_logits_ctx,  dim3(500),  dim3(256),  0, stream, oW, ob, ws, out, ws);
    hipLaunchKernelGGL(k_lse,         dim3(64),   dim3(1024), 0, stream, ws, ws);
    hipLaunchKernelGGL(k_norm,        dim3(500),  dim3(1024), 0, stream, ws, out);
}

// Round 8
// 182.351 us; speedup vs baseline: 1.4118x; 1.1684x over previous
//
#include <hip/hip_runtime.h>
#include <math.h>

#define NV 32000
#define NE 1024
#define NH 1024
#define NS 1024
#define NB 64

typedef __attribute__((ext_vector_type(4))) float f32x4;
typedef __attribute__((ext_vector_type(8))) short bf16x8;

// d_out layout (floats): output(B,V) | context(B,H) | hidden(1,B,H) | attn(B,1,S)
#define OUT_CTX   (NB*NV)
#define OUT_HID   (NB*NV + NB*NH)
#define OUT_ATTN  (NB*NV + 2*NB*NH)

// workspace layout (float offsets)
#define WS_XA   0                          // ushort[64][2048] x0 bf16, FRAGMENT-ORDERED
#define WS_HA   (WS_XA + 65536)            // ushort[64][1024] h_prev bf16, FRAGMENT-ORDERED
#define WS_PG   (WS_HA + 32768)            // f32 [12][3072][64] GRU partials
#define WS_E    (WS_PG + 12*3072*64)       // f32 [64][1024] raw energies
#define WS_PCTX (WS_E + NB*NS)             // f32 [64][64][1024] attn ctx partials (b, g, h)
#define WS_ML   (WS_PCTX + 64*64*1024)     // f32 [64][64][2]  (m, l) per (b, g)
#define WS_LA   (WS_ML + 8192)             // ushort[64][2048] concat(h,ctx) bf16, FRAGMENT-ORDERED
#define WS_ML2  (WS_LA + 65536)            // f32 [64][2048][2] logits chunk (m,l) per (row, vt)
#define WS_LSE  (WS_ML2 + 64*2048*2)       // f32 [64] lse per row
#define WS_P    (WS_LSE + 64)              // f32 [2000][1024] logits h-half partials, tile-blocked

// fragment-ordered offset (in shorts) for a [64][K] bf16 activation matrix:
// off(row,k) = ((k>>5)*4 + ((k>>3)&3))*512 + row*8 + (k&7)
// GEMM wave reads: base = A + kg*512 + col*8;  af(m,k0) = base + (k0>>5)*2048 + m*128

__device__ inline unsigned short f2bf(float f) {
    unsigned u = __builtin_bit_cast(unsigned, f);
    u += 0x7fffu + ((u >> 16) & 1u);   // RNE
    return (unsigned short)(u >> 16);
}

__device__ inline bf16x8 cvt8(float4 a, float4 b) {
    bf16x8 r;
    r[0] = (short)f2bf(a.x); r[1] = (short)f2bf(a.y);
    r[2] = (short)f2bf(a.z); r[3] = (short)f2bf(a.w);
    r[4] = (short)f2bf(b.x); r[5] = (short)f2bf(b.y);
    r[6] = (short)f2bf(b.z); r[7] = (short)f2bf(b.w);
    return r;
}

__device__ inline void store_bf4(unsigned short* p, float4 v) {
    ushort4 u = make_ushort4(f2bf(v.x), f2bf(v.y), f2bf(v.z), f2bf(v.w));
    *(ushort4*)p = u;
}

// ---------------- prep: x0 = concat(emb, lctx), h_prev -> bf16, fragment-ordered ----------------
__global__ void k_prep(const int* __restrict__ wi, const float* __restrict__ lctx,
                       const float* __restrict__ lhid, const float* __restrict__ emb,
                       float* __restrict__ ws) {
    int b = blockIdx.x, t = threadIdx.x;           // 64 x 256
    unsigned short* XA = (unsigned short*)(ws + WS_XA);
    unsigned short* HA = (unsigned short*)(ws + WS_HA);
    long row = wi[b];
    float4 e4 = ((const float4*)(emb + row*NE))[t];
    float4 c4 = ((const float4*)(lctx + (long)b*NH))[t];
    float4 h4 = ((const float4*)(lhid + (long)b*NH))[t];
    // k = 4t: (k>>5)=t>>3, ((k>>3)&3)=(t>>1)&3, (k&7)=4*(t&1)
    int o1 = ((t>>3)*4 + ((t>>1)&3))*512 + b*8 + 4*(t&1);
    // k = 1024+4t: (k>>5)=32+(t>>3)
    int o2 = ((32 + (t>>3))*4 + ((t>>1)&3))*512 + b*8 + 4*(t&1);
    store_bf4(XA + o1, e4);
    store_bf4(XA + o2, c4);
    store_bf4(HA + o1, h4);
}

// ---------------- GRU GEMM via MFMA: partials [12][3072][64], K-chunks of 256 ----------------
__global__ void __launch_bounds__(256) k_gru_mfma(const float* __restrict__ w_ih,
                                                  const float* __restrict__ w_hh,
                                                  float* __restrict__ ws) {
    int wave = blockIdx.x*4 + (threadIdx.x >> 6);   // 2304 waves (576 blocks)
    int lane = threadIdx.x & 63;
    int c = wave % 12, ntile = wave / 12;           // 192 n-tiles
    int n0 = ntile * 16;
    int col = lane & 15, kg = lane >> 4;
    const unsigned short* XA = (const unsigned short*)(ws + WS_XA);
    const unsigned short* HA = (const unsigned short*)(ws + WS_HA);
    const float* Wp; const unsigned short* Af; int ld, kbase;
    if (c < 8) { Wp = w_ih; Af = XA; ld = 2048; kbase = c*256; }
    else       { Wp = w_hh; Af = HA; ld = 1024; kbase = (c-8)*256; }
    const float* wrow = Wp + (long)(n0 + col)*ld + kbase + kg*8;
    const unsigned short* ap = Af + (kbase>>5)*2048 + kg*512 + col*8;
    f32x4 acc[4];
    #pragma unroll
    for (int m = 0; m < 4; m++) acc[m] = (f32x4){0.f,0.f,0.f,0.f};
    #pragma unroll 4
    for (int k0 = 0; k0 < 256; k0 += 32) {
        float4 wa = *(const float4*)(wrow + k0);
        float4 wb = *(const float4*)(wrow + k0 + 4);
        bf16x8 bfv = cvt8(wa, wb);
        const unsigned short* a0 = ap + (k0>>5)*2048;
        #pragma unroll
        for (int m = 0; m < 4; m++) {
            bf16x8 af = *(const bf16x8*)(a0 + m*128);
            acc[m] = __builtin_amdgcn_mfma_f32_16x16x32_bf16(af, bfv, acc[m], 0, 0, 0);
        }
    }
    float* pg = ws + WS_PG + ((long)c*3072 + n0 + col)*64;
    #pragma unroll
    for (int m = 0; m < 4; m++)
        #pragma unroll
        for (int j = 0; j < 4; j++)
            pg[m*16 + kg*4 + j] = acc[m][j];
}

// ---------------- GRU gates ----------------
__global__ void k_gates(const float* __restrict__ wsc, const float* __restrict__ b_ih,
                        const float* __restrict__ b_hh, const float* __restrict__ lhid,
                        float* __restrict__ out, float* __restrict__ ws) {
    int g = blockIdx.x*256 + threadIdx.x;  // 65536 threads
    int b = g & 63, i = g >> 6;
    float gir=0.f, giz=0.f, gin=0.f, ghr=0.f, ghz=0.f, ghn=0.f;
    #pragma unroll
    for (int c = 0; c < 8; c++) {
        long base = WS_PG + (long)c*3072*64;
        gir += wsc[base + ((long)(0*NH + i))*64 + b];
        giz += wsc[base + ((long)(1*NH + i))*64 + b];
        gin += wsc[base + ((long)(2*NH + i))*64 + b];
    }
    #pragma unroll
    for (int c = 8; c < 12; c++) {
        long base = WS_PG + (long)c*3072*64;
        ghr += wsc[base + ((long)(0*NH + i))*64 + b];
        ghz += wsc[base + ((long)(1*NH + i))*64 + b];
        ghn += wsc[base + ((long)(2*NH + i))*64 + b];
    }
    gir += b_ih[i];        ghr += b_hh[i];
    giz += b_ih[NH + i];   ghz += b_hh[NH + i];
    gin += b_ih[2*NH + i]; ghn += b_hh[2*NH + i];
    float r = 1.f / (1.f + expf(-(gir + ghr)));
    float z = 1.f / (1.f + expf(-(giz + ghz)));
    float n = tanhf(gin + r*ghn);
    float hp = lhid[(long)b*NH + i];
    float h = (1.f - z)*n + z*hp;
    out[OUT_HID + (long)b*NH + i] = h;
    // fragment-ordered LA write (k = i, row = b)
    ((unsigned short*)(ws + WS_LA))[((i>>5)*4 + ((i>>3)&3))*512 + b*8 + (i&7)] = f2bf(h);
}

// ---------------- fused: attention pass + logits h-half GEMM (independent streams) ----------------
__global__ void __launch_bounds__(256) k_attn_logh(const float* __restrict__ enc,
                                                   const float* __restrict__ oW,
                                                   const float* __restrict__ out,
                                                   float* __restrict__ ws) {
    int widx = threadIdx.x >> 6, lane = threadIdx.x & 63;
    if (blockIdx.x < 500) {
        // ---- logits h-half: vt = blockIdx.x*4 + widx, K = 0..1023 ----
        int vt = blockIdx.x*4 + widx;
        int v0 = vt * 16;
        int col = lane & 15, kg = lane >> 4;
        const unsigned short* LA = (const unsigned short*)(ws + WS_LA);
        const float* wrow = oW + (long)(v0 + col)*2048 + kg*8;
        const unsigned short* ap = LA + kg*512 + col*8;
        f32x4 acc[4];
        #pragma unroll
        for (int m = 0; m < 4; m++) acc[m] = (f32x4){0.f,0.f,0.f,0.f};
        #pragma unroll 4
        for (int k0 = 0; k0 < 1024; k0 += 32) {
            float4 wa = *(const float4*)(wrow + k0);
            float4 wb = *(const float4*)(wrow + k0 + 4);
            bf16x8 bfv = cvt8(wa, wb);
            const unsigned short* a0 = ap + (k0>>5)*2048;
            #pragma unroll
            for (int m = 0; m < 4; m++) {
                bf16x8 af = *(const bf16x8*)(a0 + m*128);
                acc[m] = __builtin_amdgcn_mfma_f32_16x16x32_bf16(af, bfv, acc[m], 0, 0, 0);
            }
        }
        float* P = ws + WS_P + (long)vt*1024;
        #pragma unroll
        for (int m = 0; m < 4; m++)
            #pragma unroll
            for (int j = 0; j < 4; j++)
                P[(m*16 + kg*4 + j)*16 + col] = acc[m][j];
        return;
    }
    // ---- attention: b, g from remaining 1024 blocks ----
    int blk = blockIdx.x - 500;
    int b = blk >> 4;
    int g = (blk & 15)*4 + widx;             // 0..63
    const float4* hr = (const float4*)(out + OUT_HID + (long)b*NH);
    float4 h0 = hr[lane], h1 = hr[64+lane], h2 = hr[128+lane], h3 = hr[192+lane];
    float m = -1e30f, l = 0.f;
    float4 c0 = make_float4(0,0,0,0), c1 = c0, c2 = c0, c3 = c0;
    const float4* vp = (const float4*)(enc + ((long)(g*16)*NB + b)*NH);
    const long sstr = (long)NB*NH/4;         // float4 stride between s
    float4 a0 = vp[lane], a1 = vp[64+lane], a2 = vp[128+lane], a3 = vp[192+lane];
    #pragma unroll
    for (int si = 0; si < 16; si++) {
        float4 n0 = a0, n1 = a1, n2 = a2, n3 = a3;
        if (si < 15) {
            const float4* np = vp + (long)(si+1)*sstr;
            n0 = np[lane]; n1 = np[64+lane]; n2 = np[128+lane]; n3 = np[192+lane];
        }
        float d = a0.x*h0.x + a0.y*h0.y + a0.z*h0.z + a0.w*h0.w
                + a1.x*h1.x + a1.y*h1.y + a1.z*h1.z + a1.w*h1.w
                + a2.x*h2.x + a2.y*h2.y + a2.z*h2.z + a2.w*h2.w
                + a3.x*h3.x + a3.y*h3.y + a3.z*h3.z + a3.w*h3.w;
        #pragma unroll
        for (int o = 32; o > 0; o >>= 1) d += __shfl_xor(d, o);
        if (lane == 0) ws[WS_E + (long)b*NS + g*16 + si] = d;
        // defer-max: rescale only when d exceeds running max by > 8 (wave-uniform branch)
        if (d > m + 8.f) {
            float coef = expf(m - d);       // m=-1e30 first time -> coef = 0
            l *= coef;
            c0.x *= coef; c0.y *= coef; c0.z *= coef; c0.w *= coef;
            c1.x *= coef; c1.y *= coef; c1.z *= coef; c1.w *= coef;
            c2.x *= coef; c2.y *= coef; c2.z *= coef; c2.w *= coef;
            c3.x *= coef; c3.y *= coef; c3.z *= coef; c3.w *= coef;
            m = d;
        }
        float p = expf(d - m);               // bounded by e^8
        l += p;
        c0.x += p*a0.x; c0.y += p*a0.y; c0.z += p*a0.z; c0.w += p*a0.w;
        c1.x += p*a1.x; c1.y += p*a1.y; c1.z += p*a1.z; c1.w += p*a1.w;
        c2.x += p*a2.x; c2.y += p*a2.y; c2.z += p*a2.z; c2.w += p*a2.w;
        c3.x += p*a3.x; c3.y += p*a3.y; c3.z += p*a3.z; c3.w += p*a3.w;
        a0 = n0; a1 = n1; a2 = n2; a3 = n3;
    }
    float* pc = ws + WS_PCTX + ((long)b*64 + g)*1024;
    *(float4*)(pc + 0*256 + lane*4) = c0;
    *(float4*)(pc + 1*256 + lane*4) = c1;
    *(float4*)(pc + 2*256 + lane*4) = c2;
    *(float4*)(pc + 3*256 + lane*4) = c3;
    if (lane == 0) {
        ws[WS_ML + ((long)b*64 + g)*2]     = m;
        ws[WS_ML + ((long)b*64 + g)*2 + 1] = l;
    }
}

// ---------------- attn reduce (wide): 256 blocks = (b, quarter) ----------------
__global__ void k_attn_reduce(const float* __restrict__ wsc, float* __restrict__ out,
                              float* __restrict__ ws) {
    int b = blockIdx.x >> 2, q = blockIdx.x & 3;   // 256 blocks x 256 threads
    int t = threadIdx.x;
    __shared__ float sm[64], sl[64], sc[64];
    __shared__ float sM, sinvL;
    if (t < 64) {
        sm[t] = wsc[WS_ML + ((long)b*64 + t)*2];
        sl[t] = wsc[WS_ML + ((long)b*64 + t)*2 + 1];
    }
    __syncthreads();
    if (t == 0) {
        float M = -1e30f;
        for (int g = 0; g < 64; g++) M = fmaxf(M, sm[g]);
        float L = 0.f;
        for (int g = 0; g < 64; g++) L += sl[g]*expf(sm[g] - M);
        sM = M; sinvL = 1.f/L;
    }
    __syncthreads();
    float M = sM, invL = sinvL;
    if (t < 64) sc[t] = expf(sm[t] - M);
    __syncthreads();
    int h = q*256 + t;
    float acc = 0.f;
    #pragma unroll 8
    for (int g = 0; g < 64; g++)
        acc += sc[g] * wsc[WS_PCTX + ((long)b*64 + g)*1024 + h];
    float ctx = acc * invL;
    out[OUT_CTX + (long)b*NH + h] = ctx;
    // fragment-ordered LA write (k = 1024+h, row = b)
    int k = 1024 + h;
    ((unsigned short*)(ws + WS_LA))[((k>>5)*4 + ((k>>3)&3))*512 + b*8 + (k&7)] = f2bf(ctx);
    int s = q*256 + t;
    float e = wsc[WS_E + (long)b*NS + s];
    out[OUT_ATTN + (long)b*NS + s] = expf(e - M)*invL;
}

// ---------------- logits ctx-half + partial + bias -> out, chunk (m,l) ----------------
__global__ void __launch_bounds__(256) k_logits_ctx(const float* __restrict__ oW,
                                                    const float* __restrict__ ob,
                                                    const float* __restrict__ wsc,
                                                    float* __restrict__ out,
                                                    float* __restrict__ ws) {
    int widx = threadIdx.x >> 6, lane = threadIdx.x & 63;
    int vt = blockIdx.x*4 + widx;           // 0..1999
    int v0 = vt * 16;
    int col = lane & 15, kg = lane >> 4;
    const unsigned short* LA = (const unsigned short*)(wsc + WS_LA);
    const float* wrow = oW + (long)(v0 + col)*2048 + 1024 + kg*8;
    const unsigned short* ap = LA + 32*2048 + kg*512 + col*8;   // k-base 1024
    f32x4 acc[4];
    #pragma unroll
    for (int m = 0; m < 4; m++) acc[m] = (f32x4){0.f,0.f,0.f,0.f};
    #pragma unroll 4
    for (int k0 = 0; k0 < 1024; k0 += 32) {
        float4 wa = *(const float4*)(wrow + k0);
        float4 wb = *(const float4*)(wrow + k0 + 4);
        bf16x8 bfv = cvt8(wa, wb);
        const unsigned short* a0 = ap + (k0>>5)*2048;
        #pragma unroll
        for (int m = 0; m < 4; m++) {
            bf16x8 af = *(const bf16x8*)(a0 + m*128);
            acc[m] = __builtin_amdgcn_mfma_f32_16x16x32_bf16(af, bfv, acc[m], 0, 0, 0);
        }
    }
    const float* P = wsc + WS_P + (long)vt*1024;
    float bias = ob[v0 + col];
    #pragma unroll
    for (int m = 0; m < 4; m++) {
        #pragma unroll
        for (int j = 0; j < 4; j++) {
            int row = m*16 + kg*4 + j;
            float v = acc[m][j] + P[row*16 + col] + bias;
            out[(long)row*NV + v0 + col] = v;
            float mx = v;
            mx = fmaxf(mx, __shfl_xor(mx, 1));
            mx = fmaxf(mx, __shfl_xor(mx, 2));
            mx = fmaxf(mx, __shfl_xor(mx, 4));
            mx = fmaxf(mx, __shfl_xor(mx, 8));
            float p = expf(v - mx);
            p += __shfl_xor(p, 1);
            p += __shfl_xor(p, 2);
            p += __shfl_xor(p, 4);
            p += __shfl_xor(p, 8);
            if (col == 0)
                *(float2*)(ws + WS_ML2 + ((long)row*2048 + vt)*2) = make_float2(mx, p);
        }
    }
}

// ---------------- fused lse + normalize: 512 blocks = (b, oct) ----------------
__global__ void __launch_bounds__(256) k_lsenorm(const float* __restrict__ wsc,
                                                 float* __restrict__ out) {
    int b = blockIdx.x >> 3, oct = blockIdx.x & 7;  // 512 blocks x 256 threads
    int t = threadIdx.x;
    __shared__ float sm_[256], sl_[256];
    const float2* ml = (const float2*)(wsc + WS_ML2 + (long)b*4096);
    float m = -1e30f, l = 0.f;
    for (int c = t; c < 2000; c += 256) {
        float2 v = ml[c];
        float mn = fmaxf(m, v.x);
        l = l*expf(m - mn) + v.y*expf(v.x - mn);
        m = mn;
    }
    sm_[t] = m; sl_[t] = l; __syncthreads();
    for (int o = 128; o > 0; o >>= 1) {
        if (t < o) {
            float m2 = sm_[t+o], l2 = sl_[t+o];
            float mn = fmaxf(sm_[t], m2);
            sl_[t] = sl_[t]*expf(sm_[t] - mn) + l2*expf(m2 - mn);
            sm_[t] = mn;
        }
        __syncthreads();
    }
    float lse = sm_[0] + logf(sl_[0]);
    // normalize this (b, oct) slice: 4000 floats = 1000 float4
    float4* row4 = (float4*)(out + (long)b*NV + oct*4000);
    #pragma unroll
    for (int j = 0; j < 4; j++) {
        int idx = t + j*256;
        if (idx < 1000) {
            float4 v = row4[idx];
            row4[idx] = make_float4(v.x-lse, v.y-lse, v.z-lse, v.w-lse);
        }
    }
}

extern "C" void kernel_launch(void* const* d_in, const int* in_sizes, int n_in,
                              void* d_out, int out_size, void* d_ws, size_t ws_size,
                              hipStream_t stream) {
    const int*   wi   = (const int*)d_in[0];
    const float* lctx = (const float*)d_in[1];
    const float* lhid = (const float*)d_in[2];
    const float* enc  = (const float*)d_in[3];
    const float* emb  = (const float*)d_in[4];
    const float* w_ih = (const float*)d_in[5];
    const float* w_hh = (const float*)d_in[6];
    const float* b_ih = (const float*)d_in[7];
    const float* b_hh = (const float*)d_in[8];
    const float* oW   = (const float*)d_in[9];
    const float* ob   = (const float*)d_in[10];
    float* out = (float*)d_out;
    float* ws  = (float*)d_ws;

    hipLaunchKernelGGL(k_prep,        dim3(64),   dim3(256), 0, stream, wi, lctx, lhid, emb, ws);
    hipLaunchKernelGGL(k_gru_mfma,    dim3(576),  dim3(256), 0, stream, w_ih, w_hh, ws);
    hipLaunchKernelGGL(k_gates,       dim3(256),  dim3(256), 0, stream, ws, b_ih, b_hh, lhid, out, ws);
    hipLaunchKernelGGL(k_attn_logh,   dim3(1524), dim3(256), 0, stream, enc, oW, out, ws);
    hipLaunchKernelGGL(k_attn_reduce, dim3(256),  dim3(256), 0, stream, ws, out, ws);
    hipLaunchKernelGGL(k_logits_ctx,  dim3(500),  dim3(256), 0, stream, oW, ob, ws, out, ws);
    hipLaunchKernelGGL(k_lsenorm,     dim3(512),  dim3(256), 0, stream, ws, out);
}